// Round 16
// baseline (742.774 us; speedup 1.0000x reference)
//
#include <hip/hip_runtime.h>
#include <hip/hip_bf16.h>
#include <cstdint>

#define DIM   2048
#define MROWS 16384  // B*S = 8*2048
#define PLANE (MROWS * (size_t)DIM)

typedef __bf16 bf16x8 __attribute__((ext_vector_type(8)));
typedef float  f32x4  __attribute__((ext_vector_type(4)));
typedef unsigned short u16;
typedef unsigned int   u32;

#define BARRIER() asm volatile("s_barrier" ::: "memory")
#define WAITVM(N) asm volatile("s_waitcnt vmcnt(" #N ")" ::: "memory")

// ---- buffers ----
// ws: [0,32MB) ternary W f,c,g,o | [32,96MB) x bf16 | [96,160MB) p_g -> gh (in-place)
// d_out: [0,128MB) o — used as p_f|p_c scratch before gemm2 | [128,256MB) h

__device__ __forceinline__ u16 ternary_bits(float w) {
    u32 u = __float_as_uint(w);
    u16 s = (u16)((u >> 16) & 0x8000u);
    return (__builtin_fabsf(w) < 0.33f) ? (u16)0 : (u16)(0x3F80u | s);
}

__device__ __forceinline__ u16 f2bf_rne(float f) {
    u32 u = __float_as_uint(f);
    u32 r = (u + 0x7FFFu + ((u >> 16) & 1u)) >> 16;
    return (u16)r;
}

__device__ __forceinline__ float bf2f(u16 v) {
    u32 u = ((u32)v) << 16;
    return __uint_as_float(u);
}

__device__ __forceinline__ void gload16(const void* g, void* l) {
    __builtin_amdgcn_global_load_lds(
        (const __attribute__((address_space(1))) void*)g,
        (__attribute__((address_space(3))) void*)l,
        16, 0, 0);
}

// ---------------- prep kernels ----------------

__global__ void prep_weights(const float* __restrict__ wf, const float* __restrict__ wc,
                             const float* __restrict__ wg, const float* __restrict__ wo,
                             u16* __restrict__ out) {
    const float* srcs[4] = {wf, wc, wg, wo};
    const float* src = srcs[blockIdx.y];
    u16* dst = out + (size_t)blockIdx.y * (DIM * DIM);
    int e = (blockIdx.x * 256 + threadIdx.x) * 8;
    float4 v0 = *(const float4*)(src + e);
    float4 v1 = *(const float4*)(src + e + 4);
    ushort4 o0, o1;
    o0.x = ternary_bits(v0.x); o0.y = ternary_bits(v0.y);
    o0.z = ternary_bits(v0.z); o0.w = ternary_bits(v0.w);
    o1.x = ternary_bits(v1.x); o1.y = ternary_bits(v1.y);
    o1.z = ternary_bits(v1.z); o1.w = ternary_bits(v1.w);
    *(ushort4*)(dst + e)     = o0;
    *(ushort4*)(dst + e + 4) = o1;
}

__global__ void cast_x(const float* __restrict__ x, u16* __restrict__ xb) {
    size_t e = ((size_t)blockIdx.x * 256 + threadIdx.x) * 8;
    float4 v0 = *(const float4*)(x + e);
    float4 v1 = *(const float4*)(x + e + 4);
    ushort4 o0, o1;
    o0.x = f2bf_rne(v0.x); o0.y = f2bf_rne(v0.y);
    o0.z = f2bf_rne(v0.z); o0.w = f2bf_rne(v0.w);
    o1.x = f2bf_rne(v1.x); o1.y = f2bf_rne(v1.y);
    o1.z = f2bf_rne(v1.z); o1.w = f2bf_rne(v1.w);
    *(ushort4*)(xb + e)     = o0;
    *(ushort4*)(xb + e + 4) = o1;
}

// ---------------- 8-phase 256x256 GEMM (m201-style port) ----------------
// 512 thr = 8 waves (2M x 4N). Per-wave out 128x64 (acc[8][4] f32x4 = 128 VGPR).
// K = 2048 = 32 tiles of BK=64; each tile = 2 k32-halves.
// LDS 128 KB: region(buf b, khalf h) = 32KB: A[256 rows][32 k] 16KB + B same.
// Phase(ks, nh): { ds_read A(8, at nh==0 only) + B(2); issue 1 half-tile stage
//   (2 gloads); [WAITVM(8) at phases 2,4]; BARRIER; 16 MFMA (setprio); BARRIER }
// Stage schedule (steady, tile t): P1: A-k1(t+1); P2: B-k1(t+1); P3: A-k0(t+2);
//   P4: B-k0(t+2). Regions written are free (last read 1-2 phases earlier,
//   behind a barrier). FIFO audit (per wave, 2 loads/issue):
//   - end P2(t), before P3 reads k1(t) [issued P1(t-1),P2(t-1)]: outstanding =
//     P3(t-1),P4(t-1),P1(t),P2(t) = 8 -> WAITVM(8) retires through P2(t-1). OK
//   - end P4(t), before P1(t+1) reads k0(t+1) [issued P3(t-1),P4(t-1)]:
//     outstanding = P1..P4(t) = 8 -> WAITVM(8) retires through P4(t-1). OK
// Tail: t=30 P4 -> WAITVM(4) (retires k0(31)); t=31 P2 -> WAITVM(0).
// Staging linear-dest + source chunk-XOR involution (R5-proven, 0 conflicts).
// PRE mode: bf16 preacts via LDS-routed coalesced store (fixes R14's 2.5x
// write amplification). Else: f32 + bias direct.

template<bool PRE>
__global__ __launch_bounds__(512) void gemm8p(
    const u16* __restrict__ Amat,   // [M][2048] bf16
    const u16* __restrict__ Wmat,   // [N][2048] bf16 ternary
    u16* __restrict__ pf, u16* __restrict__ pc, u16* __restrict__ pg,
    const float* __restrict__ bias, float* __restrict__ oout)
{
    __shared__ __align__(16) u16 lds[65536];   // 128 KB

    const int tid  = threadIdx.x;
    const int lane = tid & 63;
    const int wave = tid >> 6;
    const int wm   = wave >> 2;   // 0..1
    const int wn   = wave & 3;    // 0..3

    const int CPX  = PRE ? 192 : 64;            // blocks per XCD chunk
    const int swz  = (blockIdx.x & 7) * CPX + (blockIdx.x >> 3);
    const int brow = (swz & 63) * 256;
    const int bcol = (swz >> 6) * 256;

    const int gc4  = (tid & 3) ^ ((tid >> 3) & 3);  // swizzled source chunk
    const int fr   = lane & 15;
    const int hi   = lane >> 4;
    const int csw  = (hi ^ ((fr >> 1) & 3)) * 8;    // swizzled read chunk (u16)

    f32x4 acc[8][4] = {};

    const u16* aSrc = Amat + (size_t)(brow + (tid >> 2)) * DIM;
    const u16* bSrc = Wmat + (size_t)(bcol + (tid >> 2)) * DIM;

    // region(b,h) u16 offset = b*32768 + h*16384; A at +0, B at +8192
    auto stA = [&](int b, int h, int t) {
        const int k0 = t * 64 + h * 32;
        u16* dst = &lds[b * 32768 + h * 16384 + tid * 8];
        gload16(aSrc + k0 + gc4 * 8, dst);
        gload16(aSrc + (size_t)128 * DIM + k0 + gc4 * 8, dst + 4096);
    };
    auto stB = [&](int b, int h, int t) {
        const int k0 = t * 64 + h * 32;
        u16* dst = &lds[b * 32768 + h * 16384 + 8192 + tid * 8];
        gload16(bSrc + k0 + gc4 * 8, dst);
        gload16(bSrc + (size_t)128 * DIM + k0 + gc4 * 8, dst + 4096);
    };

    auto rdA = [&](int b, int h, bf16x8 (&a)[8]) {
        const u16* p = &lds[b * 32768 + h * 16384];
        #pragma unroll
        for (int mi = 0; mi < 8; ++mi)
            a[mi] = *(const bf16x8*)(p + (wm * 128 + mi * 16 + fr) * 32 + csw);
    };
    auto rdB = [&](int b, int h, int nh, bf16x8 (&bb)[2]) {
        const u16* p = &lds[b * 32768 + h * 16384 + 8192];
        #pragma unroll
        for (int j = 0; j < 2; ++j)
            bb[j] = *(const bf16x8*)(p + (wn * 64 + (nh * 2 + j) * 16 + fr) * 32 + csw);
    };
    auto mf = [&](bf16x8 (&a)[8], bf16x8 (&bb)[2], int nh) {
        __builtin_amdgcn_s_setprio(1);
        #pragma unroll
        for (int j = 0; j < 2; ++j)
            #pragma unroll
            for (int mi = 0; mi < 8; ++mi)
                acc[mi][nh * 2 + j] =
                    __builtin_amdgcn_mfma_f32_16x16x32_bf16(a[mi], bb[j], acc[mi][nh * 2 + j], 0, 0, 0);
        __builtin_amdgcn_s_setprio(0);
    };

    bf16x8 a[8], bb[2];

    // prologue: A-k0(0),B-k0(0),A-k1(0),B-k1(0),A-k0(1),B-k0(1); retire k0(0)
    stA(0, 0, 0); stB(0, 0, 0);
    stA(0, 1, 0); stB(0, 1, 0);
    stA(1, 0, 1); stB(1, 0, 1);
    WAITVM(8);
    BARRIER();

    #pragma unroll 1
    for (int t = 0; t < 30; ++t) {
        const int b = t & 1, bn = b ^ 1;
        // P1 (ks0, nh0)
        rdA(b, 0, a); rdB(b, 0, 0, bb);
        stA(bn, 1, t + 1);
        BARRIER();
        mf(a, bb, 0);
        BARRIER();
        // P2 (ks0, nh1)
        rdB(b, 0, 1, bb);
        stB(bn, 1, t + 1);
        WAITVM(8);
        BARRIER();
        mf(a, bb, 1);
        BARRIER();
        // P3 (ks1, nh0)
        rdA(b, 1, a); rdB(b, 1, 0, bb);
        stA(b, 0, t + 2);
        BARRIER();
        mf(a, bb, 0);
        BARRIER();
        // P4 (ks1, nh1)
        rdB(b, 1, 1, bb);
        stB(b, 0, t + 2);
        WAITVM(8);
        BARRIER();
        mf(a, bb, 1);
        BARRIER();
    }
    { // t = 30 (buf0): P1,P2 issue k1(31); P3,P4 no issue
        rdA(0, 0, a); rdB(0, 0, 0, bb);
        stA(1, 1, 31);
        BARRIER(); mf(a, bb, 0); BARRIER();
        rdB(0, 0, 1, bb);
        stB(1, 1, 31);
        WAITVM(8);
        BARRIER(); mf(a, bb, 1); BARRIER();
        rdA(0, 1, a); rdB(0, 1, 0, bb);
        BARRIER(); mf(a, bb, 0); BARRIER();
        rdB(0, 1, 1, bb);
        WAITVM(4);    // retire A-k0(31),B-k0(31)
        BARRIER(); mf(a, bb, 1); BARRIER();
    }
    { // t = 31 (buf1): no issues
        rdA(1, 0, a); rdB(1, 0, 0, bb);
        BARRIER(); mf(a, bb, 0); BARRIER();
        rdB(1, 0, 1, bb);
        WAITVM(0);    // retire A-k1(31),B-k1(31)
        BARRIER(); mf(a, bb, 1); BARRIER();
        rdA(1, 1, a); rdB(1, 1, 0, bb);
        BARRIER(); mf(a, bb, 0); BARRIER();
        rdB(1, 1, 1, bb);
        mf(a, bb, 1);
    }

    if (PRE) {
        // bf16 preacts via LDS-routed coalesced store
        BARRIER();
        #pragma unroll
        for (int mi = 0; mi < 8; ++mi)
            #pragma unroll
            for (int ni = 0; ni < 4; ++ni)
                #pragma unroll
                for (int j = 0; j < 4; ++j)
                    lds[(wm * 128 + mi * 16 + hi * 4 + j) * 256 + wn * 64 + ni * 16 + fr] =
                        f2bf_rne(acc[mi][ni][j]);
        BARRIER();
        const int gate = bcol >> 11;
        const int colb = bcol & 2047;
        u16* outp = (gate == 0) ? pf : (gate == 1) ? pc : pg;
        const int rr = tid >> 5;          // 0..15
        const int cc = (tid & 31) * 8;    // u16 chunk in row
        #pragma unroll
        for (int rg = 0; rg < 16; ++rg) {
            const int row = rg * 16 + rr;
            bf16x8 v = *(const bf16x8*)(&lds[row * 256 + cc]);
            *(bf16x8*)(outp + (size_t)(brow + row) * DIM + colb + cc) = v;
        }
    } else {
        // f32 + bias direct
        #pragma unroll
        for (int ni = 0; ni < 4; ++ni) {
            const int col = bcol + wn * 64 + ni * 16 + fr;
            const float bv = bias[col];
            #pragma unroll
            for (int mi = 0; mi < 8; ++mi)
                #pragma unroll
                for (int j = 0; j < 4; ++j)
                    oout[(size_t)(brow + wm * 128 + mi * 16 + hi * 4 + j) * DIM + col] =
                        acc[mi][ni][j] + bv;
        }
    }
}

// ---------------- fuse_gates: f/c/g -> h, gh (elementwise, HBM-bound) ----------------

__global__ __launch_bounds__(256) void fuse_gates(
    const u16* __restrict__ pf, const u16* __restrict__ pc, const u16* __restrict__ pg,
    const float* __restrict__ bfv_, const float* __restrict__ bcv_, const float* __restrict__ bgv_,
    const float* __restrict__ hprev,
    float* __restrict__ hout,
    u16* __restrict__ gh)
{
    #pragma unroll 1
    for (int it = 0; it < 4; ++it) {
        const size_t u = (size_t)blockIdx.x * 256 + threadIdx.x + (size_t)it * 1048576;
        const size_t e = u * 8;
        const int col = (int)(e & 2047);

        ushort4 f0 = *(const ushort4*)(pf + e), f1 = *(const ushort4*)(pf + e + 4);
        ushort4 c0 = *(const ushort4*)(pc + e), c1 = *(const ushort4*)(pc + e + 4);
        ushort4 g0 = *(const ushort4*)(pg + e), g1 = *(const ushort4*)(pg + e + 4);
        float4 hp0 = *(const float4*)(hprev + e), hp1 = *(const float4*)(hprev + e + 4);
        float4 bf0 = *(const float4*)(bfv_ + col), bf1 = *(const float4*)(bfv_ + col + 4);
        float4 bc0 = *(const float4*)(bcv_ + col), bc1 = *(const float4*)(bcv_ + col + 4);
        float4 bg0 = *(const float4*)(bgv_ + col), bg1 = *(const float4*)(bgv_ + col + 4);

        float4 h0, h1;
        ushort4 o0, o1;

        #define DO_ELEM(V, HP, PF, PC, PG, BF, BC, BG, OUT)                   \
        {                                                                      \
            float pfv = bf2f(PF) + (BF);                                       \
            float pcv = bf2f(PC) + (BC);                                       \
            float pgv = bf2f(PG) + (BG);                                       \
            float f  = 1.f / (1.f + __expf(-pfv));                             \
            float cc = pcv / (1.f + __expf(-pcv));                             \
            float g  = 1.f / (1.f + __expf(-pgv));                             \
            float hh = f * (HP) + (1.f - f) * cc;                              \
            V = hh;                                                            \
            OUT = f2bf_rne(g * hh);                                            \
        }
        DO_ELEM(h0.x, hp0.x, f0.x, c0.x, g0.x, bf0.x, bc0.x, bg0.x, o0.x);
        DO_ELEM(h0.y, hp0.y, f0.y, c0.y, g0.y, bf0.y, bc0.y, bg0.y, o0.y);
        DO_ELEM(h0.z, hp0.z, f0.z, c0.z, g0.z, bf0.z, bc0.z, bg0.z, o0.z);
        DO_ELEM(h0.w, hp0.w, f0.w, c0.w, g0.w, bf0.w, bc0.w, bg0.w, o0.w);
        DO_ELEM(h1.x, hp1.x, f1.x, c1.x, g1.x, bf1.x, bc1.x, bg1.x, o1.x);
        DO_ELEM(h1.y, hp1.y, f1.y, c1.y, g1.y, bf1.y, bc1.y, bg1.y, o1.y);
        DO_ELEM(h1.z, hp1.z, f1.z, c1.z, g1.z, bf1.z, bc1.z, bg1.z, o1.z);
        DO_ELEM(h1.w, hp1.w, f1.w, c1.w, g1.w, bf1.w, bc1.w, bg1.w, o1.w);
        #undef DO_ELEM

        *(float4*)(hout + e)     = h0;
        *(float4*)(hout + e + 4) = h1;
        *(ushort4*)(gh + e)      = o0;
        *(ushort4*)(gh + e + 4)  = o1;
    }
}

extern "C" void kernel_launch(void* const* d_in, const int* in_sizes, int n_in,
                              void* d_out, int out_size, void* d_ws, size_t ws_size,
                              hipStream_t stream) {
    const float* x  = (const float*)d_in[0];
    const float* hp = (const float*)d_in[1];
    const float* wf = (const float*)d_in[2];
    const float* bf = (const float*)d_in[3];
    const float* wc = (const float*)d_in[4];
    const float* bc = (const float*)d_in[5];
    const float* wg = (const float*)d_in[6];
    const float* bg = (const float*)d_in[7];
    const float* wo = (const float*)d_in[8];
    const float* bo = (const float*)d_in[9];

    float* o_out = (float*)d_out;
    float* h_out = o_out + PLANE;

    u16* w_t  = (u16*)d_ws;                              // wf,wc,wg then wo (32MB)
    u16* x_bf = (u16*)((char*)d_ws + 33554432);          // 64MB
    u16* gh   = (u16*)((char*)d_ws + 100663296);         // 64MB (p_g, then gh in-place)

    u16* p_f = (u16*)o_out;                              // o-half scratch
    u16* p_c = p_f + PLANE;

    prep_weights<<<dim3(2048, 4), 256, 0, stream>>>(wf, wc, wg, wo, w_t);
    cast_x<<<dim3(16384), 256, 0, stream>>>(x, x_bf);
    gemm8p<true><<<dim3(1536), 512, 0, stream>>>(x_bf, w_t, p_f, p_c, gh, nullptr, nullptr);
    fuse_gates<<<dim3(4096), 256, 0, stream>>>(p_f, p_c, gh, bf, bc, bg, hp, h_out, gh);
    gemm8p<false><<<dim3(512), 512, 0, stream>>>(gh, w_t + 3 * (size_t)DIM * DIM,
                                                 nullptr, nullptr, nullptr, bo, o_out);
}

// Round 17
// 694.305 us; speedup vs baseline: 1.0698x; 1.0698x over previous
//
#include <hip/hip_runtime.h>
#include <hip/hip_bf16.h>
#include <cstdint>

#define DIM   2048
#define MROWS 16384  // B*S = 8*2048
#define PLANE (MROWS * (size_t)DIM)

typedef __bf16 bf16x8 __attribute__((ext_vector_type(8)));
typedef float  f32x4  __attribute__((ext_vector_type(4)));
typedef unsigned short u16;
typedef unsigned int   u32;

#define BARRIER() asm volatile("s_barrier" ::: "memory")
#define WAITVM(N) asm volatile("s_waitcnt vmcnt(" #N ")" ::: "memory")

// ---- buffers ----
// ws: [0,32MB) ternary W f,c,g,o | [32,96MB) x bf16 | [96,160MB) p_g -> gh (in-place)
// d_out: [0,128MB) o — used as p_f|p_c scratch before gemm2 | [128,256MB) h

__device__ __forceinline__ u16 ternary_bits(float w) {
    u32 u = __float_as_uint(w);
    u16 s = (u16)((u >> 16) & 0x8000u);
    return (__builtin_fabsf(w) < 0.33f) ? (u16)0 : (u16)(0x3F80u | s);
}

__device__ __forceinline__ u16 f2bf_rne(float f) {
    u32 u = __float_as_uint(f);
    u32 r = (u + 0x7FFFu + ((u >> 16) & 1u)) >> 16;
    return (u16)r;
}

__device__ __forceinline__ float bf2f(u16 v) {
    u32 u = ((u32)v) << 16;
    return __uint_as_float(u);
}

__device__ __forceinline__ void gload16(const void* g, void* l) {
    __builtin_amdgcn_global_load_lds(
        (const __attribute__((address_space(1))) void*)g,
        (__attribute__((address_space(3))) void*)l,
        16, 0, 0);
}

// ---------------- prep kernels ----------------

__global__ void prep_weights(const float* __restrict__ wf, const float* __restrict__ wc,
                             const float* __restrict__ wg, const float* __restrict__ wo,
                             u16* __restrict__ out) {
    const float* srcs[4] = {wf, wc, wg, wo};
    const float* src = srcs[blockIdx.y];
    u16* dst = out + (size_t)blockIdx.y * (DIM * DIM);
    int e = (blockIdx.x * 256 + threadIdx.x) * 8;
    float4 v0 = *(const float4*)(src + e);
    float4 v1 = *(const float4*)(src + e + 4);
    ushort4 o0, o1;
    o0.x = ternary_bits(v0.x); o0.y = ternary_bits(v0.y);
    o0.z = ternary_bits(v0.z); o0.w = ternary_bits(v0.w);
    o1.x = ternary_bits(v1.x); o1.y = ternary_bits(v1.y);
    o1.z = ternary_bits(v1.z); o1.w = ternary_bits(v1.w);
    *(ushort4*)(dst + e)     = o0;
    *(ushort4*)(dst + e + 4) = o1;
}

__global__ void cast_x(const float* __restrict__ x, u16* __restrict__ xb) {
    size_t e = ((size_t)blockIdx.x * 256 + threadIdx.x) * 8;
    float4 v0 = *(const float4*)(x + e);
    float4 v1 = *(const float4*)(x + e + 4);
    ushort4 o0, o1;
    o0.x = f2bf_rne(v0.x); o0.y = f2bf_rne(v0.y);
    o0.z = f2bf_rne(v0.z); o0.w = f2bf_rne(v0.w);
    o1.x = f2bf_rne(v1.x); o1.y = f2bf_rne(v1.y);
    o1.z = f2bf_rne(v1.z); o1.w = f2bf_rne(v1.w);
    *(ushort4*)(xb + e)     = o0;
    *(ushort4*)(xb + e + 4) = o1;
}

// ---------------- 8-phase 256x256 GEMM (m201-style port) ----------------
// Structure identical to R16 (which measured MfmaUtil 44.3%, WRITE exactly 196MB).
// R17 change: PRE-mode grid traversal is n-fastest-of-3 within each XCD chunk —
// 3 consecutive blocks share one 1MB A-tile (L2-hit) and the chunk's 3 W strips
// (3MB) stay L2-resident, fixing the 811MB-vs-90MB-ideal A over-fetch that
// stalled the 8-phase pipe (prefetch slack ~460cy covers L2 ~200cy, not HBM ~900cy).

template<bool PRE>
__global__ __launch_bounds__(512) void gemm8p(
    const u16* __restrict__ Amat,   // [M][2048] bf16
    const u16* __restrict__ Wmat,   // [N][2048] bf16 ternary
    u16* __restrict__ pf, u16* __restrict__ pc, u16* __restrict__ pg,
    const float* __restrict__ bias, float* __restrict__ oout)
{
    __shared__ __align__(16) u16 lds[65536];   // 128 KB

    const int tid  = threadIdx.x;
    const int lane = tid & 63;
    const int wave = tid >> 6;
    const int wm   = wave >> 2;   // 0..1
    const int wn   = wave & 3;    // 0..3

    const int xcd   = blockIdx.x & 7;
    const int inner = blockIdx.x >> 3;
    int mtile, ntile;
    if (PRE) { ntile = xcd * 3 + inner % 3; mtile = inner / 3; }   // n-fastest
    else     { ntile = xcd;                 mtile = inner;     }   // 1 n-tile/XCD
    const int brow = mtile * 256;
    const int bcol = ntile * 256;

    const int gc4  = (tid & 3) ^ ((tid >> 3) & 3);  // swizzled source chunk
    const int fr   = lane & 15;
    const int hi   = lane >> 4;
    const int csw  = (hi ^ ((fr >> 1) & 3)) * 8;    // swizzled read chunk (u16)

    f32x4 acc[8][4] = {};

    const u16* aSrc = Amat + (size_t)(brow + (tid >> 2)) * DIM;
    const u16* bSrc = Wmat + (size_t)(bcol + (tid >> 2)) * DIM;

    // region(b,h) u16 offset = b*32768 + h*16384; A at +0, B at +8192
    auto stA = [&](int b, int h, int t) {
        const int k0 = t * 64 + h * 32;
        u16* dst = &lds[b * 32768 + h * 16384 + tid * 8];
        gload16(aSrc + k0 + gc4 * 8, dst);
        gload16(aSrc + (size_t)128 * DIM + k0 + gc4 * 8, dst + 4096);
    };
    auto stB = [&](int b, int h, int t) {
        const int k0 = t * 64 + h * 32;
        u16* dst = &lds[b * 32768 + h * 16384 + 8192 + tid * 8];
        gload16(bSrc + k0 + gc4 * 8, dst);
        gload16(bSrc + (size_t)128 * DIM + k0 + gc4 * 8, dst + 4096);
    };

    auto rdA = [&](int b, int h, bf16x8 (&a)[8]) {
        const u16* p = &lds[b * 32768 + h * 16384];
        #pragma unroll
        for (int mi = 0; mi < 8; ++mi)
            a[mi] = *(const bf16x8*)(p + (wm * 128 + mi * 16 + fr) * 32 + csw);
    };
    auto rdB = [&](int b, int h, int nh, bf16x8 (&bb)[2]) {
        const u16* p = &lds[b * 32768 + h * 16384 + 8192];
        #pragma unroll
        for (int j = 0; j < 2; ++j)
            bb[j] = *(const bf16x8*)(p + (wn * 64 + (nh * 2 + j) * 16 + fr) * 32 + csw);
    };
    auto mf = [&](bf16x8 (&a)[8], bf16x8 (&bb)[2], int nh) {
        __builtin_amdgcn_s_setprio(1);
        #pragma unroll
        for (int j = 0; j < 2; ++j)
            #pragma unroll
            for (int mi = 0; mi < 8; ++mi)
                acc[mi][nh * 2 + j] =
                    __builtin_amdgcn_mfma_f32_16x16x32_bf16(a[mi], bb[j], acc[mi][nh * 2 + j], 0, 0, 0);
        __builtin_amdgcn_s_setprio(0);
    };

    bf16x8 a[8], bb[2];

    // prologue: A-k0(0),B-k0(0),A-k1(0),B-k1(0),A-k0(1),B-k0(1); retire k0(0)
    stA(0, 0, 0); stB(0, 0, 0);
    stA(0, 1, 0); stB(0, 1, 0);
    stA(1, 0, 1); stB(1, 0, 1);
    WAITVM(8);
    BARRIER();

    #pragma unroll 1
    for (int t = 0; t < 30; ++t) {
        const int b = t & 1, bn = b ^ 1;
        // P1 (ks0, nh0)
        rdA(b, 0, a); rdB(b, 0, 0, bb);
        stA(bn, 1, t + 1);
        BARRIER();
        mf(a, bb, 0);
        BARRIER();
        // P2 (ks0, nh1)
        rdB(b, 0, 1, bb);
        stB(bn, 1, t + 1);
        WAITVM(8);
        BARRIER();
        mf(a, bb, 1);
        BARRIER();
        // P3 (ks1, nh0)
        rdA(b, 1, a); rdB(b, 1, 0, bb);
        stA(b, 0, t + 2);
        BARRIER();
        mf(a, bb, 0);
        BARRIER();
        // P4 (ks1, nh1)
        rdB(b, 1, 1, bb);
        stB(b, 0, t + 2);
        WAITVM(8);
        BARRIER();
        mf(a, bb, 1);
        BARRIER();
    }
    { // t = 30 (buf0): P1,P2 issue k1(31); P3,P4 no issue
        rdA(0, 0, a); rdB(0, 0, 0, bb);
        stA(1, 1, 31);
        BARRIER(); mf(a, bb, 0); BARRIER();
        rdB(0, 0, 1, bb);
        stB(1, 1, 31);
        WAITVM(8);
        BARRIER(); mf(a, bb, 1); BARRIER();
        rdA(0, 1, a); rdB(0, 1, 0, bb);
        BARRIER(); mf(a, bb, 0); BARRIER();
        rdB(0, 1, 1, bb);
        WAITVM(4);    // retire A-k0(31),B-k0(31)
        BARRIER(); mf(a, bb, 1); BARRIER();
    }
    { // t = 31 (buf1): no issues
        rdA(1, 0, a); rdB(1, 0, 0, bb);
        BARRIER(); mf(a, bb, 0); BARRIER();
        rdB(1, 0, 1, bb);
        WAITVM(0);    // retire A-k1(31),B-k1(31)
        BARRIER(); mf(a, bb, 1); BARRIER();
        rdA(1, 1, a); rdB(1, 1, 0, bb);
        BARRIER(); mf(a, bb, 0); BARRIER();
        rdB(1, 1, 1, bb);
        mf(a, bb, 1);
    }

    if (PRE) {
        // bf16 preacts via LDS-routed coalesced store
        BARRIER();
        #pragma unroll
        for (int mi = 0; mi < 8; ++mi)
            #pragma unroll
            for (int ni = 0; ni < 4; ++ni)
                #pragma unroll
                for (int j = 0; j < 4; ++j)
                    lds[(wm * 128 + mi * 16 + hi * 4 + j) * 256 + wn * 64 + ni * 16 + fr] =
                        f2bf_rne(acc[mi][ni][j]);
        BARRIER();
        const int gate = bcol >> 11;
        const int colb = bcol & 2047;
        u16* outp = (gate == 0) ? pf : (gate == 1) ? pc : pg;
        const int rr = tid >> 5;          // 0..15
        const int cc = (tid & 31) * 8;    // u16 chunk in row
        #pragma unroll
        for (int rg = 0; rg < 16; ++rg) {
            const int row = rg * 16 + rr;
            bf16x8 v = *(const bf16x8*)(&lds[row * 256 + cc]);
            *(bf16x8*)(outp + (size_t)(brow + row) * DIM + colb + cc) = v;
        }
    } else {
        // f32 + bias direct
        #pragma unroll
        for (int ni = 0; ni < 4; ++ni) {
            const int col = bcol + wn * 64 + ni * 16 + fr;
            const float bv = bias[col];
            #pragma unroll
            for (int mi = 0; mi < 8; ++mi)
                #pragma unroll
                for (int j = 0; j < 4; ++j)
                    oout[(size_t)(brow + wm * 128 + mi * 16 + hi * 4 + j) * DIM + col] =
                        acc[mi][ni][j] + bv;
        }
    }
}

// ---------------- fuse_gates: f/c/g -> h, gh (elementwise, HBM-bound) ----------------

__global__ __launch_bounds__(256) void fuse_gates(
    const u16* __restrict__ pf, const u16* __restrict__ pc, const u16* __restrict__ pg,
    const float* __restrict__ bfv_, const float* __restrict__ bcv_, const float* __restrict__ bgv_,
    const float* __restrict__ hprev,
    float* __restrict__ hout,
    u16* __restrict__ gh)
{
    #pragma unroll 1
    for (int it = 0; it < 4; ++it) {
        const size_t u = (size_t)blockIdx.x * 256 + threadIdx.x + (size_t)it * 1048576;
        const size_t e = u * 8;
        const int col = (int)(e & 2047);

        ushort4 f0 = *(const ushort4*)(pf + e), f1 = *(const ushort4*)(pf + e + 4);
        ushort4 c0 = *(const ushort4*)(pc + e), c1 = *(const ushort4*)(pc + e + 4);
        ushort4 g0 = *(const ushort4*)(pg + e), g1 = *(const ushort4*)(pg + e + 4);
        float4 hp0 = *(const float4*)(hprev + e), hp1 = *(const float4*)(hprev + e + 4);
        float4 bf0 = *(const float4*)(bfv_ + col), bf1 = *(const float4*)(bfv_ + col + 4);
        float4 bc0 = *(const float4*)(bcv_ + col), bc1 = *(const float4*)(bcv_ + col + 4);
        float4 bg0 = *(const float4*)(bgv_ + col), bg1 = *(const float4*)(bgv_ + col + 4);

        float4 h0, h1;
        ushort4 o0, o1;

        #define DO_ELEM(V, HP, PF, PC, PG, BF, BC, BG, OUT)                   \
        {                                                                      \
            float pfv = bf2f(PF) + (BF);                                       \
            float pcv = bf2f(PC) + (BC);                                       \
            float pgv = bf2f(PG) + (BG);                                       \
            float f  = 1.f / (1.f + __expf(-pfv));                             \
            float cc = pcv / (1.f + __expf(-pcv));                             \
            float g  = 1.f / (1.f + __expf(-pgv));                             \
            float hh = f * (HP) + (1.f - f) * cc;                              \
            V = hh;                                                            \
            OUT = f2bf_rne(g * hh);                                            \
        }
        DO_ELEM(h0.x, hp0.x, f0.x, c0.x, g0.x, bf0.x, bc0.x, bg0.x, o0.x);
        DO_ELEM(h0.y, hp0.y, f0.y, c0.y, g0.y, bf0.y, bc0.y, bg0.y, o0.y);
        DO_ELEM(h0.z, hp0.z, f0.z, c0.z, g0.z, bf0.z, bc0.z, bg0.z, o0.z);
        DO_ELEM(h0.w, hp0.w, f0.w, c0.w, g0.w, bf0.w, bc0.w, bg0.w, o0.w);
        DO_ELEM(h1.x, hp1.x, f1.x, c1.x, g1.x, bf1.x, bc1.x, bg1.x, o1.x);
        DO_ELEM(h1.y, hp1.y, f1.y, c1.y, g1.y, bf1.y, bc1.y, bg1.y, o1.y);
        DO_ELEM(h1.z, hp1.z, f1.z, c1.z, g1.z, bf1.z, bc1.z, bg1.z, o1.z);
        DO_ELEM(h1.w, hp1.w, f1.w, c1.w, g1.w, bf1.w, bc1.w, bg1.w, o1.w);
        #undef DO_ELEM

        *(float4*)(hout + e)     = h0;
        *(float4*)(hout + e + 4) = h1;
        *(ushort4*)(gh + e)      = o0;
        *(ushort4*)(gh + e + 4)  = o1;
    }
}

extern "C" void kernel_launch(void* const* d_in, const int* in_sizes, int n_in,
                              void* d_out, int out_size, void* d_ws, size_t ws_size,
                              hipStream_t stream) {
    const float* x  = (const float*)d_in[0];
    const float* hp = (const float*)d_in[1];
    const float* wf = (const float*)d_in[2];
    const float* bf = (const float*)d_in[3];
    const float* wc = (const float*)d_in[4];
    const float* bc = (const float*)d_in[5];
    const float* wg = (const float*)d_in[6];
    const float* bg = (const float*)d_in[7];
    const float* wo = (const float*)d_in[8];
    const float* bo = (const float*)d_in[9];

    float* o_out = (float*)d_out;
    float* h_out = o_out + PLANE;

    u16* w_t  = (u16*)d_ws;                              // wf,wc,wg then wo (32MB)
    u16* x_bf = (u16*)((char*)d_ws + 33554432);          // 64MB
    u16* gh   = (u16*)((char*)d_ws + 100663296);         // 64MB (p_g, then gh in-place)

    u16* p_f = (u16*)o_out;                              // o-half scratch
    u16* p_c = p_f + PLANE;

    prep_weights<<<dim3(2048, 4), 256, 0, stream>>>(wf, wc, wg, wo, w_t);
    cast_x<<<dim3(16384), 256, 0, stream>>>(x, x_bf);
    gemm8p<true><<<dim3(1536), 512, 0, stream>>>(x_bf, w_t, p_f, p_c, gh, nullptr, nullptr);
    fuse_gates<<<dim3(4096), 256, 0, stream>>>(p_f, p_c, gh, bf, bc, bg, hp, h_out, gh);
    gemm8p<false><<<dim3(512), 512, 0, stream>>>(gh, w_t + 3 * (size_t)DIM * DIM,
                                                 nullptr, nullptr, nullptr, bo, o_out);
}